// Round 1
// baseline (239.876 us; speedup 1.0000x reference)
//
#include <hip/hip_runtime.h>
#include <hip/hip_bf16.h>

typedef __attribute__((ext_vector_type(8))) short bf16x8_t;
typedef __attribute__((ext_vector_type(4))) float f32x4_t;
typedef unsigned short u16;
typedef unsigned int u32;

__device__ __forceinline__ u16 f2bf(float f) {
  union { float f; u32 u; } v; v.f = f;
  u32 u = v.u;
  return (u16)((u + 0x7fffu + ((u >> 16) & 1u)) >> 16);
}

// ---------------- setup kernels ----------------

// Wq fp32 [512][256] -> bf16 [512][256]
__global__ void k_cvt_wq(const float* __restrict__ Wq, u16* __restrict__ Wq_bf) {
  int i = blockIdx.x * 256 + threadIdx.x;  // float4 index, 32768 total
  float4 v = reinterpret_cast<const float4*>(Wq)[i];
  uint2 p;
  p.x = (u32)f2bf(v.x) | ((u32)f2bf(v.y) << 16);
  p.y = (u32)f2bf(v.z) | ((u32)f2bf(v.w) << 16);
  reinterpret_cast<uint2*>(Wq_bf)[i] = p;
}

// kvp[b][l][j] = sum_c kv[b][l][c] * Wkv[j][c]   (grid: (jc=16, lt=11, b=2), 256 thr)
__global__ void k_kvp(const float* __restrict__ kv, const float* __restrict__ Wkv,
                      float* __restrict__ kvp) {
  __shared__ float kvL[7 * 768];
  const int b = blockIdx.z, lt = blockIdx.y, jc = blockIdx.x;
  const int tid = threadIdx.x;
  const float* kvb = kv + ((size_t)b * 77 + (size_t)lt * 7) * 768;
  for (int i = tid; i < 7 * 768 / 4; i += 256)
    reinterpret_cast<float4*>(kvL)[i] = reinterpret_cast<const float4*>(kvb)[i];
  __syncthreads();
  const int j = jc * 64 + (tid & 63);
  const int lgc = tid >> 6;              // wave id 0..3 (wave-uniform)
  const bool has1 = (lgc < 3);           // 7 rows = 4 + 3
  float a0 = 0.f, a1 = 0.f;
  const float4* Wr = reinterpret_cast<const float4*>(Wkv + (size_t)j * 768);
  const float4* k0 = reinterpret_cast<const float4*>(kvL + lgc * 768);
  const float4* k1 = reinterpret_cast<const float4*>(kvL + (lgc + 4) * 768);
  #pragma unroll 4
  for (int k4 = 0; k4 < 192; ++k4) {
    float4 wv = Wr[k4];
    float4 x0 = k0[k4];
    a0 += wv.x * x0.x + wv.y * x0.y + wv.z * x0.z + wv.w * x0.w;
    if (has1) {
      float4 x1 = k1[k4];
      a1 += wv.x * x1.x + wv.y * x1.y + wv.z * x1.z + wv.w * x1.w;
    }
  }
  const int lbase = b * 77 + lt * 7;
  kvp[(size_t)(lbase + lgc) * 1024 + j] = a0;
  if (has1) kvp[(size_t)(lbase + lgc + 4) * 1024 + j] = a1;
}

// k-softmax over tokens + context[b][h][d][e]   (grid: (h=8, b=2), 256 thr)
__global__ void k_ctx(const float* __restrict__ kvp, float* __restrict__ ctx) {
  __shared__ float ks[77 * 64];
  __shared__ float vs[77 * 64];
  __shared__ float red[4 * 64];
  __shared__ float mcol[64], icol[64];
  const int h = blockIdx.x, b = blockIdx.y;
  const int tid = threadIdx.x;
  const float* base = kvp + (size_t)b * 77 * 1024;
  for (int i = tid; i < 77 * 64; i += 256) {
    int ll = i >> 6, d = i & 63;
    ks[i] = base[(size_t)ll * 1024 + h * 64 + d];
    vs[i] = base[(size_t)ll * 1024 + 512 + h * 64 + d];
  }
  __syncthreads();
  const int d = tid & 63, part = tid >> 6;
  float m = -1e30f;
  for (int ll = part; ll < 77; ll += 4) m = fmaxf(m, ks[ll * 64 + d]);
  red[part * 64 + d] = m;
  __syncthreads();
  float mfull = fmaxf(fmaxf(red[d], red[64 + d]), fmaxf(red[128 + d], red[192 + d]));
  float s = 0.f;
  for (int ll = part; ll < 77; ll += 4) s += __expf(ks[ll * 64 + d] - mfull);
  __syncthreads();
  red[part * 64 + d] = s;
  __syncthreads();
  if (part == 0) {
    float S = red[d] + red[64 + d] + red[128 + d] + red[192 + d];
    mcol[d] = mfull;
    icol[d] = 1.0f / S;
  }
  __syncthreads();
  for (int i = tid; i < 77 * 64; i += 256) {
    int dd = i & 63;
    ks[i] = __expf(ks[i] - mcol[dd]) * icol[dd];
  }
  __syncthreads();
  const int dg = tid & 15, eg = tid >> 4;
  float acc[4][4];
  #pragma unroll
  for (int a = 0; a < 4; ++a)
    #pragma unroll
    for (int c = 0; c < 4; ++c) acc[a][c] = 0.f;
  for (int ll = 0; ll < 77; ++ll) {
    float4 kk = *reinterpret_cast<const float4*>(ks + ll * 64 + dg * 4);
    float4 vv = *reinterpret_cast<const float4*>(vs + ll * 64 + eg * 4);
    float kd[4] = {kk.x, kk.y, kk.z, kk.w};
    float ve[4] = {vv.x, vv.y, vv.z, vv.w};
    #pragma unroll
    for (int di = 0; di < 4; ++di)
      #pragma unroll
      for (int ei = 0; ei < 4; ++ei) acc[di][ei] += kd[di] * ve[ei];
  }
  float* cb = ctx + (size_t)(b * 8 + h) * 4096;
  #pragma unroll
  for (int di = 0; di < 4; ++di) {
    float4 row;
    row.x = acc[di][0]; row.y = acc[di][1]; row.z = acc[di][2]; row.w = acc[di][3];
    *reinterpret_cast<float4*>(cb + (size_t)(dg * 4 + di) * 64 + eg * 4) = row;
  }
}

// M_bf[b][h][o][d] = sum_e Wout[o][h*64+e] * ctx[b][h][d][e]  (grid: (oc=4, h=8, b=2))
__global__ void k_M(const float* __restrict__ ctx, const float* __restrict__ Wout,
                    u16* __restrict__ M_bf) {
  __shared__ float Wt[64 * 68];   // [e][o_local], padded
  __shared__ float ct[64 * 68];   // [e][d], padded
  const int oc = blockIdx.x, h = blockIdx.y, b = blockIdx.z;
  const int tid = threadIdx.x;
  for (int i = tid; i < 4096; i += 256) {
    int ol = i >> 6, e = i & 63;
    Wt[e * 68 + ol] = Wout[(size_t)(oc * 64 + ol) * 512 + h * 64 + e];
  }
  const float* cbase = ctx + (size_t)(b * 8 + h) * 4096;
  for (int i = tid; i < 4096; i += 256) {
    int dd = i >> 6, e = i & 63;
    ct[e * 68 + dd] = cbase[(size_t)dd * 64 + e];
  }
  __syncthreads();
  const int og = tid & 15, dg = tid >> 4;
  float acc[4][4];  // [oi][di]
  #pragma unroll
  for (int a = 0; a < 4; ++a)
    #pragma unroll
    for (int c = 0; c < 4; ++c) acc[a][c] = 0.f;
  for (int e = 0; e < 64; ++e) {
    float4 wv = *reinterpret_cast<const float4*>(Wt + e * 68 + og * 4);
    float4 cv = *reinterpret_cast<const float4*>(ct + e * 68 + dg * 4);
    float wo[4] = {wv.x, wv.y, wv.z, wv.w};
    float cd[4] = {cv.x, cv.y, cv.z, cv.w};
    #pragma unroll
    for (int oi = 0; oi < 4; ++oi)
      #pragma unroll
      for (int di = 0; di < 4; ++di) acc[oi][di] += wo[oi] * cd[di];
  }
  #pragma unroll
  for (int oi = 0; oi < 4; ++oi) {
    int o = oc * 64 + og * 4 + oi;
    uint2 p;
    p.x = (u32)f2bf(acc[oi][0]) | ((u32)f2bf(acc[oi][1]) << 16);
    p.y = (u32)f2bf(acc[oi][2]) | ((u32)f2bf(acc[oi][3]) << 16);
    *reinterpret_cast<uint2*>(M_bf + ((size_t)((b * 8 + h) * 256 + o)) * 64 + dg * 4) = p;
  }
}

// ---------------- fused main kernel ----------------
// out[b][o][n] = bout[o] + sum_h M_h[o][:] @ (softmax_d(Wq_h @ x[b][:][n]) * 0.125)
// 512 threads = 8 waves, BN=128 pixels/block, grid (512, 2)
__global__ __launch_bounds__(512, 2) void k_main(
    const float* __restrict__ x, const u16* __restrict__ Wq_bf,
    const u16* __restrict__ M_bf, const float* __restrict__ bout,
    float* __restrict__ out) {
  extern __shared__ char smem[];
  u16* Xl = reinterpret_cast<u16*>(smem);                 // [128 n][256 c] bf16 swizzled, 64 KB
  u16* QT = reinterpret_cast<u16*>(smem + 65536);         // [128 n][64 d] bf16 swizzled, 16 KB
  u16* WM = reinterpret_cast<u16*>(smem + 81920);         // Wl [64][256] or Ml [256][64], 32 KB
  float* sred = reinterpret_cast<float*>(smem + 114688);  // [2 wm][2 kind][128 col]

  const int tid = threadIdx.x;
  const int w = tid >> 6;
  const int l = tid & 63;
  const int lg = l >> 4;
  const int l15 = l & 15;

  const int b = blockIdx.y;
  const int n0 = blockIdx.x * 128;
  const float* xb = x + (size_t)b * 256 * 65536 + n0;

  // ---- stage X tile: global fp32 [c][n] -> LDS bf16 [n][c] (XOR-swizzled)
  {
    const int n = tid & 127;
    const int cq = tid >> 7;  // 0..3
    #pragma unroll 4
    for (int it = 0; it < 16; ++it) {
      const int c0 = it * 16 + cq * 4;
      float f0 = xb[(size_t)(c0 + 0) * 65536 + n];
      float f1 = xb[(size_t)(c0 + 1) * 65536 + n];
      float f2 = xb[(size_t)(c0 + 2) * 65536 + n];
      float f3 = xb[(size_t)(c0 + 3) * 65536 + n];
      uint2 p;
      p.x = (u32)f2bf(f0) | ((u32)f2bf(f1) << 16);
      p.y = (u32)f2bf(f2) | ((u32)f2bf(f3) << 16);
      u32 boff = (u32)n * 512u + (((u32)c0 * 2u) ^ (((u32)n & 7u) << 4));
      *reinterpret_cast<uint2*>(reinterpret_cast<char*>(Xl) + boff) = p;
    }
  }

  const f32x4_t fzero = {0.f, 0.f, 0.f, 0.f};
  f32x4_t acc2[4][4];
  #pragma unroll
  for (int i = 0; i < 4; ++i)
    #pragma unroll
    for (int j = 0; j < 4; ++j) acc2[i][j] = fzero;

  __syncthreads();

  const int wm1 = w >> 2, wn1 = w & 3;  // GEMM1: 2m x 4n (wave tile 32x32)
  const int wm2 = w >> 1, wn2 = w & 1;  // GEMM2: 4m x 2n (wave tile 64x64)

  for (int h = 0; h < 8; ++h) {
    __syncthreads();  // prev GEMM2 done reading WM
    // ---- stage Wl = Wq_h bf16 [64 d][256 c], swizzled
    {
      const u16* src = Wq_bf + (size_t)h * 64 * 256;
      #pragma unroll
      for (int it = 0; it < 4; ++it) {
        int fidx = tid + it * 512;
        int row = fidx >> 5, seg = fidx & 31;
        uint4 v = *reinterpret_cast<const uint4*>(src + (size_t)row * 256 + seg * 8);
        u32 boff = (u32)row * 512u + (((u32)seg * 16u) ^ (((u32)row & 7u) << 4));
        *reinterpret_cast<uint4*>(reinterpret_cast<char*>(WM) + boff) = v;
      }
    }
    __syncthreads();

    // ---- GEMM1: Q[64 d][128 n] = Wq_h @ X
    f32x4_t q[2][2];
    q[0][0] = fzero; q[0][1] = fzero; q[1][0] = fzero; q[1][1] = fzero;
    #pragma unroll
    for (int ks = 0; ks < 8; ++ks) {
      const u32 ko = (u32)(ks * 64 + lg * 16);
      bf16x8_t a0, a1, b0, b1;
      { int row = wm1 * 32 + l15;
        a0 = *reinterpret_cast<const bf16x8_t*>(reinterpret_cast<const char*>(WM) +
              (u32)row * 512u + (ko ^ (((u32)row & 7u) << 4))); }
      { int row = wm1 * 32 + 16 + l15;
        a1 = *reinterpret_cast<const bf16x8_t*>(reinterpret_cast<const char*>(WM) +
              (u32)row * 512u + (ko ^ (((u32)row & 7u) << 4))); }
      { int cn = wn1 * 32 + l15;
        b0 = *reinterpret_cast<const bf16x8_t*>(reinterpret_cast<const char*>(Xl) +
              (u32)cn * 512u + (ko ^ (((u32)cn & 7u) << 4))); }
      { int cn = wn1 * 32 + 16 + l15;
        b1 = *reinterpret_cast<const bf16x8_t*>(reinterpret_cast<const char*>(Xl) +
              (u32)cn * 512u + (ko ^ (((u32)cn & 7u) << 4))); }
      q[0][0] = __builtin_amdgcn_mfma_f32_16x16x32_bf16(a0, b0, q[0][0], 0, 0, 0);
      q[0][1] = __builtin_amdgcn_mfma_f32_16x16x32_bf16(a0, b1, q[0][1], 0, 0, 0);
      q[1][0] = __builtin_amdgcn_mfma_f32_16x16x32_bf16(a1, b0, q[1][0], 0, 0, 0);
      q[1][1] = __builtin_amdgcn_mfma_f32_16x16x32_bf16(a1, b1, q[1][1], 0, 0, 0);
    }

    // ---- softmax over 64 d per column (cross-wave via sred)
    float pm[2];
    #pragma unroll
    for (int nf = 0; nf < 2; ++nf) {
      float m = fmaxf(fmaxf(fmaxf(q[0][nf][0], q[0][nf][1]), fmaxf(q[0][nf][2], q[0][nf][3])),
                      fmaxf(fmaxf(q[1][nf][0], q[1][nf][1]), fmaxf(q[1][nf][2], q[1][nf][3])));
      m = fmaxf(m, __shfl_xor(m, 16, 64));
      m = fmaxf(m, __shfl_xor(m, 32, 64));
      pm[nf] = m;
    }
    if (lg == 0) {
      sred[(wm1 * 2 + 0) * 128 + wn1 * 32 + l15] = pm[0];
      sred[(wm1 * 2 + 0) * 128 + wn1 * 32 + 16 + l15] = pm[1];
    }
    __syncthreads();
    const int col0 = wn1 * 32 + l15, col1 = wn1 * 32 + 16 + l15;
    float mf0 = fmaxf(sred[0 * 128 + col0], sred[2 * 128 + col0]);
    float mf1 = fmaxf(sred[0 * 128 + col1], sred[2 * 128 + col1]);
    float ps[2] = {0.f, 0.f};
    #pragma unroll
    for (int mf = 0; mf < 2; ++mf)
      #pragma unroll
      for (int r = 0; r < 4; ++r) {
        q[mf][0][r] = __expf(q[mf][0][r] - mf0); ps[0] += q[mf][0][r];
        q[mf][1][r] = __expf(q[mf][1][r] - mf1); ps[1] += q[mf][1][r];
      }
    #pragma unroll
    for (int nf = 0; nf < 2; ++nf) {
      ps[nf] += __shfl_xor(ps[nf], 16, 64);
      ps[nf] += __shfl_xor(ps[nf], 32, 64);
    }
    if (lg == 0) {
      sred[(wm1 * 2 + 1) * 128 + col0] = ps[0];
      sred[(wm1 * 2 + 1) * 128 + col1] = ps[1];
    }
    __syncthreads();
    float sc[2];
    sc[0] = 0.125f / (sred[1 * 128 + col0] + sred[3 * 128 + col0]);
    sc[1] = 0.125f / (sred[1 * 128 + col1] + sred[3 * 128 + col1]);

    // ---- write Qsm to QT [n][d] bf16 swizzled
    #pragma unroll
    for (int mf = 0; mf < 2; ++mf)
      #pragma unroll
      for (int nf = 0; nf < 2; ++nf) {
        int col = wn1 * 32 + nf * 16 + l15;
        int row0 = wm1 * 32 + mf * 16 + lg * 4;
        uint2 p;
        p.x = (u32)f2bf(q[mf][nf][0] * sc[nf]) | ((u32)f2bf(q[mf][nf][1] * sc[nf]) << 16);
        p.y = (u32)f2bf(q[mf][nf][2] * sc[nf]) | ((u32)f2bf(q[mf][nf][3] * sc[nf]) << 16);
        u32 boff = (u32)col * 128u + (((u32)row0 * 2u) ^ (((u32)col & 7u) << 4));
        *reinterpret_cast<uint2*>(reinterpret_cast<char*>(QT) + boff) = p;
      }
    __syncthreads();

    // ---- stage Ml = M_bf[b][h] [256 o][64 d], swizzled
    {
      const u16* src = M_bf + (size_t)(b * 8 + h) * 256 * 64;
      #pragma unroll
      for (int it = 0; it < 4; ++it) {
        int fidx = tid + it * 512;
        int row = fidx >> 3, seg = fidx & 7;
        uint4 v = *reinterpret_cast<const uint4*>(src + (size_t)row * 64 + seg * 8);
        u32 boff = (u32)row * 128u + (((u32)seg * 16u) ^ (((u32)row & 7u) << 4));
        *reinterpret_cast<uint4*>(reinterpret_cast<char*>(WM) + boff) = v;
      }
    }
    __syncthreads();

    // ---- GEMM2: Out[256 o][128 n] += M_h @ Qsm
    #pragma unroll
    for (int kb = 0; kb < 2; ++kb) {
      const u32 ko = (u32)(kb * 64 + lg * 16);
      bf16x8_t a[4], bq[4];
      #pragma unroll
      for (int mf = 0; mf < 4; ++mf) {
        int row = wm2 * 64 + mf * 16 + l15;
        a[mf] = *reinterpret_cast<const bf16x8_t*>(reinterpret_cast<const char*>(WM) +
                 (u32)row * 128u + (ko ^ (((u32)row & 7u) << 4)));
      }
      #pragma unroll
      for (int nf = 0; nf < 4; ++nf) {
        int col = wn2 * 64 + nf * 16 + l15;
        bq[nf] = *reinterpret_cast<const bf16x8_t*>(reinterpret_cast<const char*>(QT) +
                  (u32)col * 128u + (ko ^ (((u32)col & 7u) << 4)));
      }
      #pragma unroll
      for (int mf = 0; mf < 4; ++mf)
        #pragma unroll
        for (int nf = 0; nf < 4; ++nf)
          acc2[mf][nf] = __builtin_amdgcn_mfma_f32_16x16x32_bf16(a[mf], bq[nf], acc2[mf][nf], 0, 0, 0);
    }
  }

  // ---- epilogue: add bias, store fp32
  #pragma unroll
  for (int mf = 0; mf < 4; ++mf) {
    #pragma unroll
    for (int r = 0; r < 4; ++r) {
      int o = wm2 * 64 + mf * 16 + lg * 4 + r;
      float bo = bout[o];
      #pragma unroll
      for (int nf = 0; nf < 4; ++nf) {
        int nn = n0 + wn2 * 64 + nf * 16 + l15;
        out[((size_t)b * 256 + o) * 65536 + nn] = acc2[mf][nf][r] + bo;
      }
    }
  }
}

extern "C" void kernel_launch(void* const* d_in, const int* in_sizes, int n_in,
                              void* d_out, int out_size, void* d_ws, size_t ws_size,
                              hipStream_t stream) {
  (void)in_sizes; (void)n_in; (void)out_size; (void)ws_size;
  const float* x    = (const float*)d_in[0];
  const float* kv   = (const float*)d_in[1];
  const float* Wq   = (const float*)d_in[2];
  const float* Wkv  = (const float*)d_in[3];
  const float* Wout = (const float*)d_in[4];
  const float* bout = (const float*)d_in[5];
  float* out = (float*)d_out;

  char* ws = (char*)d_ws;
  float* kvp   = (float*)(ws);                              // 2*77*1024*4   = 630784 B
  float* ctx   = (float*)(ws + 630784);                     // 2*8*64*64*4   = 262144 B
  u16*   M_bf  = (u16*)(ws + 630784 + 262144);              // 2*8*256*64*2  = 524288 B
  u16*   Wq_bf = (u16*)(ws + 630784 + 262144 + 524288);     // 512*256*2     = 262144 B

  hipFuncSetAttribute(reinterpret_cast<const void*>(k_main),
                      hipFuncAttributeMaxDynamicSharedMemorySize, 116736);

  k_cvt_wq<<<128, 256, 0, stream>>>(Wq, Wq_bf);
  k_kvp<<<dim3(16, 11, 2), 256, 0, stream>>>(kv, Wkv, kvp);
  k_ctx<<<dim3(8, 2), 256, 0, stream>>>(kvp, ctx);
  k_M<<<dim3(4, 8, 2), 256, 0, stream>>>(ctx, Wout, M_bf);
  k_main<<<dim3(512, 2), 512, 116736, stream>>>(x, Wq_bf, M_bf, bout, out);
}